// Round 11
// baseline (335.410 us; speedup 1.0000x reference)
//
#include <hip/hip_runtime.h>
#include <math.h>

typedef unsigned long long u64;
typedef unsigned int u32;

#define NP 34125
#define NB 4
#define NTOP 5000
#define TOPK 750
#define NW 79          // ceil(5000/64)
#define TPAD 5120      // padded top-K stride
#define CAP 8192       // slot capacity per image for counting-sort scatter
#define MWORDS 202240  // triangular mask words per image: 64*sum_{c=0..78}(79-c)

// ---- exact-order f32 IoU matching the JAX reference elementwise ops ----
__device__ __forceinline__ float iou_ref(float4 a, float4 b) {
  float areaA = __fmul_rn(__fsub_rn(a.z, a.x), __fsub_rn(a.w, a.y));
  float areaB = __fmul_rn(__fsub_rn(b.z, b.x), __fsub_rn(b.w, b.y));
  float iw = fmaxf(__fsub_rn(fminf(a.z, b.z), fmaxf(a.x, b.x)), 0.0f);
  float ih = fmaxf(__fsub_rn(fminf(a.w, b.w), fmaxf(a.y, b.y)), 0.0f);
  float inter = __fmul_rn(iw, ih);
  float denom = __fsub_rn(__fadd_rn(areaA, areaB), inter);
  return inter / denom;  // 0/0 -> NaN for zero-pad boxes; NaN>0.3f is false (safe)
}

// triangular row offset (in u64 words) of mask row i within one image
__device__ __forceinline__ int row_off_words(int i) {
  int ci = i >> 6;
  int r = i & 63;
  int base = ((ci * 79 - ((ci * (ci - 1)) >> 1)) << 6);
  return base + r * (79 - ci);
}

__device__ __forceinline__ u64 wave_or64(u64 x) {
  for (int d = 1; d < 64; d <<= 1) x |= __shfl_xor(x, d);
  return x;
}

__global__ void k_zero(float* out, u32* hist, u32* bcnt, int* cut, u64* keys) {
  int t = blockIdx.x * 256 + threadIdx.x;
  if (t < 30000) out[t] = 0.0f;
  if (t < 4096) { hist[t] = 0u; bcnt[t] = 0u; }
  if (t < 4) cut[t] = 0;
  if (t < NB * CAP) keys[t] = ~0ull;
}

__global__ void k_decode(const float4* loc, const float* conf, const float4* prior,
                         float4* dec, u32* hist) {
  int p = blockIdx.x * 256 + threadIdx.x;
  int img = blockIdx.y;
  if (p >= NP) return;
  float4 L = loc[(size_t)img * NP + p];
  float4 Pr = prior[p];
  // xy = prior_xy + (loc_xy * 0.1) * prior_wh   (no FMA contraction: explicit _rn ops)
  float ex = __fmul_rn(__fmul_rn(L.x, 0.1f), Pr.z);
  float ey = __fmul_rn(__fmul_rn(L.y, 0.1f), Pr.w);
  float cx = __fadd_rn(Pr.x, ex);
  float cy = __fadd_rn(Pr.y, ey);
  // wh = prior_wh * exp(loc_wh * 0.2) ; exp via double = correctly-rounded f32 exp
  float ww = __fmul_rn(Pr.z, (float)exp((double)__fmul_rn(L.z, 0.2f)));
  float hh = __fmul_rn(Pr.w, (float)exp((double)__fmul_rn(L.w, 0.2f)));
  float x1 = __fsub_rn(cx, __fmul_rn(ww, 0.5f));
  float y1 = __fsub_rn(cy, __fmul_rn(hh, 0.5f));
  float x2 = __fadd_rn(x1, ww);
  float y2 = __fadd_rn(y1, hh);
  dec[(size_t)img * NP + p] = make_float4(x1, y1, x2, y2);
  float s = conf[((size_t)img * NP + p) * 2 + 1];
  if (s > 0.05f) {
    int bin = (int)(s * 1024.0f); if (bin > 1023) bin = 1023;
    atomicAdd(&hist[img * 1024 + bin], 1u);
  }
}

// per image: suffix-scan the 1024-bin histogram -> descending-order base
// position per bin, plus the cutoff bin (suffix count crosses NTOP)
__global__ __launch_bounds__(1024) void k_prefix(const u32* hist, u32* sbase, int* cut) {
  __shared__ u32 buf[1024];
  int img = blockIdx.x, tid = threadIdx.x;
  int b = 1023 - tid;
  u32 c = hist[img * 1024 + b];
  buf[tid] = c;
  __syncthreads();
  for (int off = 1; off < 1024; off <<= 1) {
    u32 v = (tid >= off) ? buf[tid - off] : 0u;
    __syncthreads();
    buf[tid] += v;
    __syncthreads();
  }
  u32 S = buf[tid];                 // inclusive suffix count for bin b
  sbase[img * 1024 + b] = S - c;    // # elements in strictly-higher bins
  if (S >= NTOP && (S - c) < NTOP) cut[img] = b;  // unique crossing thread
}

// scatter each above-cutoff candidate to its exact descending position
// (bin base + arrival rank); within-bin order fixed later by k_binsort
__global__ void k_scatter(const float* conf, const u32* sbase, const int* cut,
                          u32* bcnt, u64* keys) {
  int p = blockIdx.x * 256 + threadIdx.x;
  int img = blockIdx.y;
  if (p >= NP) return;
  float s = conf[((size_t)img * NP + p) * 2 + 1];
  if (!(s > 0.05f)) return;
  int bin = (int)(s * 1024.0f); if (bin > 1023) bin = 1023;
  if (bin < cut[img]) return;
  u32 r = atomicAdd(&bcnt[img * 1024 + bin], 1u);
  u32 slot = sbase[img * 1024 + bin] + r;
  if (slot < CAP)
    keys[(size_t)img * CAP + slot] = (((u64)(~__float_as_uint(s))) << 32) | (u32)p;
}

// full ascending sort of 64 u64 keys across one wave (21 shfl_xor steps)
__device__ __forceinline__ u64 sort64(u64 x, int lane) {
  for (int k = 2; k <= 64; k <<= 1) {
    for (int j = k >> 1; j > 0; j >>= 1) {
      u64 v = __shfl_xor(x, j);
      bool keepMin = (((lane & j) == 0) == ((lane & k) == 0));
      u64 mn = x < v ? x : v;
      u64 mx = x < v ? v : x;
      x = keepMin ? mn : mx;
    }
  }
  return x;
}

// one wave per bin: sort that bin's slot range in place
// key = (~score_bits, idx) ascending  => score desc, idx asc (lax.top_k ties)
__global__ __launch_bounds__(64) void k_binsort(const u32* sbase, const u32* bcnt,
                                                const int* cut, u64* keys) {
  int b = blockIdx.x, img = blockIdx.y;
  if (b < cut[img]) return;
  u32 n = bcnt[img * 1024 + b];
  if (n == 0) return;
  u32 base = sbase[img * 1024 + b];
  if (base >= CAP) return;
  if (n > CAP - base) n = CAP - base;
  u64* seg = keys + (size_t)img * CAP + base;
  int lane = threadIdx.x;
  if (n <= 64) {
    u64 key = (lane < (int)n) ? seg[lane] : ~0ull;
    key = sort64(key, lane);
    if (lane < (int)n) seg[lane] = key;
  } else {
    // rare fallback: in-LDS bitonic, single wave, up to 1024 elements
    __shared__ u64 sbuf[1024];
    if (n > 1024) n = 1024;
    int npow2 = 128;
    while (npow2 < (int)n) npow2 <<= 1;
    for (int t = lane; t < npow2; t += 64) sbuf[t] = (t < (int)n) ? seg[t] : ~0ull;
    __syncthreads();
    for (int k = 2; k <= npow2; k <<= 1) {
      for (int j = k >> 1; j > 0; j >>= 1) {
        for (int t = lane; t < npow2; t += 64) {
          int ixj = t ^ j;
          if (ixj > t) {
            u64 a = sbuf[t], bb = sbuf[ixj];
            bool up = ((t & k) == 0);
            if ((a > bb) == up) { sbuf[t] = bb; sbuf[ixj] = a; }
          }
        }
        __syncthreads();
      }
    }
    for (int t = lane; t < (int)n; t += 64) seg[t] = sbuf[t];
  }
}

// emit sorted top-5000: scores, gathered boxes, validity bitmask
__global__ __launch_bounds__(1024) void k_emit(const u64* keys, const float4* dec,
                                               float* tscore, float4* tbox, u64* vmask) {
  int img = blockIdx.x;
  int tid = threadIdx.x;
  int lane = tid & 63;
  const u64* kimg = keys + (size_t)img * CAP;
  for (int i = tid; i < NTOP; i += 1024) {
    u64 key = kimg[i];
    u32 sb = ~(u32)(key >> 32);
    float s = __uint_as_float(sb);
    u32 pidx = (u32)(key & 0xffffffffu);
    tscore[img * TPAD + i] = s;
    float4 bx;
    if (key != ~0ull) bx = dec[(size_t)img * NP + pidx];
    else bx = make_float4(0.f, 0.f, 0.f, 0.f);
    tbox[img * TPAD + i] = bx;
    bool valid = (key != ~0ull) && (s > 0.05f);
    u64 bal = __ballot(valid);
    if (lane == 0) vmask[img * 80 + (i >> 6)] = bal;
  }
}

// parallel suppression-bitmask: 64x64 tiles, upper triangle, triangular storage.
// Diagonal blocks additionally emit the TRANSPOSED tile (lane l holds column l:
// bit k = "k suppresses l"), built with 64 ballots.
__global__ __launch_bounds__(64) void k_mask(const float4* tbox, u64* mask, u64* diagT) {
  int ci = blockIdx.x, cj = blockIdx.y, img = blockIdx.z;
  if (cj < ci) return;
  int lane = threadIdx.x;
  __shared__ float4 jb[64];
  int j0 = cj * 64;
  int jj = j0 + lane;
  jb[lane] = (jj < NTOP) ? tbox[img * TPAD + jj] : make_float4(0.f, 0.f, 0.f, 0.f);
  __syncthreads();
  int i = ci * 64 + lane;
  if (i >= NTOP) return;
  float4 bi = tbox[img * TPAD + i];
  u64 word = 0;
  for (int q = 0; q < 64; ++q) {
    int j = j0 + q;
    if (j > i && j < NTOP) {
      if (iou_ref(bi, jb[q]) > 0.3f) word |= (1ull << q);
    }
  }
  u64* mrow = mask + (size_t)img * MWORDS + row_off_words(i);
  mrow[cj - ci] = word;
  if (ci == cj) {
    u64 colw = 0ull;
    for (int t = 0; t < 64; ++t) {
      u64 b = __ballot((word >> t) & 1ull);  // bit l of b = row l's bit t => column t
      if (lane == t) colw = b;
    }
    diagT[((size_t)img * 80 + ci) * 64 + lane] = colw;
  }
}

// greedy NMS, software-pipelined with REGISTER-RESIDENT deferred staging.
// __launch_bounds__(64,1): min 1 wave/EU releases the VGPR allocator so the
// 16x2x2 u64 staging arrays live in registers (round-8 regression: capped at
// 64 VGPRs -> scratch spills on the critical path).
// Per word f (parity P): merge raw loads issued at f-2 (2-word slack) ->
// broadcast rem[f]+carry -> ballot-greedy on diagT -> carry=wave_or(superdiag)
// [register-only push to f+1] -> issue f's kept rows into parity-P raw arrays
// (consumed at f+2). Overflow >16 keeps: immediate-OR (rare).
__global__ __launch_bounds__(64, 1) void k_nms(const float* tscore, const float4* tbox,
                                               const u64* vmask, const u64* mask,
                                               const u64* diagT, float* out) {
  int img = blockIdx.x;
  int lane = threadIdx.x;
  const u64* mimg = mask + (size_t)img * MWORDS;
  const u64* dT = diagT + (size_t)img * 80 * 64;

  u64 vld_lo = (lane < NW) ? vmask[img * 80 + lane] : 0ull;
  u64 vld_hi = (lane + 64 < NW) ? vmask[img * 80 + lane + 64] : 0ull;
  u64 rem_lo = 0ull, rem_hi = 0ull;

  __shared__ int list[TOPK];
  int nk = 0;
  u64 carry = 0ull;  // contributions of word f-1's keeps to rem[f] (register-only)

  // parity-buffered 2-deep tile prefetch: c=diagT column, s=superdiag entry
  u64 c0 = dT[lane];                                            // word 0
  u64 s0 = mimg[row_off_words(lane) + 1];                       // rows of word 0, word 1
  u64 c1 = dT[64 + lane];                                       // word 1
  u64 s1 = (3 < NW) ? mimg[row_off_words(64 + lane) + 1] : 0ull;

  // parity-persistent raw staging (constant indices only; fully unrolled)
  u64 rAlo[16], rAhi[16], rBlo[16], rBhi[16];
#pragma unroll
  for (int u = 0; u < 16; ++u) { rAlo[u] = 0; rAhi[u] = 0; rBlo[u] = 0; rBhi[u] = 0; }

  auto step = [&](int f, u64 (&rLo)[16], u64 (&rHi)[16], u64& cReg, u64& sReg) -> bool {
    // 1. consume prefetched tiles; immediately reissue for word f+2
    u64 colT = cReg;
    u64 sd = sReg;
    if (f + 2 < NW) {
      cReg = dT[(f + 2) * 64 + lane];
      sReg = (f + 3 < NW) ? mimg[row_off_words(((f + 2) << 6) + lane) + 1] : 0ull;
    }

    // 2. deferred merge: raw rows issued at word f-2 (>= 2 words of slack)
#pragma unroll
    for (int u = 0; u < 16; ++u) { rem_lo |= rLo[u]; rem_hi |= rHi[u]; }

    // 3. broadcast word-f state
    u64 remf = ((f < 64) ? __shfl(rem_lo, f) : __shfl(rem_hi, f - 64)) | carry;
    u64 vldf = (f < 64) ? __shfl(vld_lo, f) : __shfl(vld_hi, f - 64);
    carry = 0ull;

    u64 live = vldf & ~remf;
    if (live == 0ull) return false;  // stale raw re-merges later: idempotent, harmless

    // 4. serial greedy via ballots on the transposed diagonal
    u64 kept = 0ull;
    while (live) {
      int k = __builtin_ctzll(live);
      kept |= (1ull << k);
      u64 sup = __ballot((colT >> k) & 1ull);  // bit l = "k suppresses l" (l>k)
      live &= ~((1ull << k) | sup);
    }

    // 5. record keeps (ascending index == greedy order), honor the 750 cut
    int cap = TOPK - nk;
    int rank = __builtin_popcountll(kept & ((1ull << lane) - 1ull));
    if (((kept >> lane) & 1ull) && rank < cap) list[nk + rank] = (f << 6) + lane;
    int nkw = __builtin_popcountll(kept);
    nk += (nkw < cap) ? nkw : cap;
    if (nk >= TOPK) return true;

    // 6. narrow push to rem[f+1]: register-only via superdiag
    carry = wave_or64(((kept >> lane) & 1ull) ? sd : 0ull);

    // 7. issue kept rows' future words (>= f+2) into parity raw staging;
    //    merged at word f+2. Overflow beyond 16 keeps: immediate OR (rare).
    int lw = lane - f;
    int hw = lane + 64 - f;
    bool lok = (lane > f + 1);
    bool hok = (lane + 64 < NW) && (lane + 64 > f + 1);
    if (f + 2 < NW) {
      u64 kk = kept;
#pragma unroll
      for (int u = 0; u < 16; ++u) {
        if (kk) {
          int cur = (f << 6) + __builtin_ctzll(kk);
          kk &= kk - 1ull;
          const u64* row = mimg + row_off_words(cur);
          rLo[u] = lok ? row[lw] : 0ull;
          rHi[u] = hok ? row[hw] : 0ull;
        } else {
          rLo[u] = 0ull;
          rHi[u] = 0ull;
        }
      }
      while (kk) {  // rare: >16 keeps in one word
        int k2 = __builtin_ctzll(kk);
        kk &= kk - 1ull;
        const u64* row = mimg + row_off_words((f << 6) + k2);
        if (lok) rem_lo |= row[lw];
        if (hok) rem_hi |= row[hw];
      }
    }
    return false;
  };

  for (int f = 0; f < NW; ++f) {
    bool done = (f & 1) ? step(f, rBlo, rBhi, c1, s1)
                        : step(f, rAlo, rAhi, c0, s0);
    if (done) break;
  }

  __syncthreads();
  float* o = out + (size_t)(img * 2 + 1) * TOPK * 5;
  for (int r = lane; r < nk; r += 64) {
    int i = list[r];
    float s = tscore[img * TPAD + i];
    float4 b = tbox[img * TPAD + i];
    o[r * 5 + 0] = s;
    o[r * 5 + 1] = b.x;
    o[r * 5 + 2] = b.y;
    o[r * 5 + 3] = b.z;
    o[r * 5 + 4] = b.w;
  }
}

extern "C" void kernel_launch(void* const* d_in, const int* in_sizes, int n_in,
                              void* d_out, int out_size, void* d_ws, size_t ws_size,
                              hipStream_t stream) {
  const float4* loc   = (const float4*)d_in[0];
  const float*  conf  = (const float*)d_in[1];
  const float4* prior = (const float4*)d_in[2];
  float* out = (float*)d_out;
  char* ws = (char*)d_ws;

  // ws layout (256B-aligned offsets), total ~9.55MB
  float4* dec    = (float4*)(ws + 0);          // 4*34125*16 = 2,184,000
  u32*    hist   = (u32*)  (ws + 2184192);     // 4*1024*4   = 16,384
  u32*    bcnt   = (u32*)  (ws + 2200576);     // 4*1024*4   = 16,384
  u32*    sbase  = (u32*)  (ws + 2216960);     // 4*1024*4   = 16,384
  int*    cut    = (int*)  (ws + 2233344);     // 16 (pad to 256)
  u64*    keys   = (u64*)  (ws + 2233600);     // 4*8192*8   = 262,144
  float*  tscore = (float*)(ws + 2495744);     // 4*5120*4   = 81,920
  float4* tbox   = (float4*)(ws + 2577664);    // 4*5120*16  = 327,680
  u64*    vmaskp = (u64*)  (ws + 2905344);     // 4*80*8     = 2,560 (pad to 2,908,160)
  u64*    maskp  = (u64*)  (ws + 2908160);     // 4*202240*8 = 6,471,680 -> 9,379,840
  u64*    diagTp = (u64*)  (ws + 9379840);     // 4*80*64*8  = 163,840   -> 9,543,680

  k_zero<<<dim3(128), 256, 0, stream>>>(out, hist, bcnt, cut, keys);
  k_decode<<<dim3((NP + 255) / 256, NB), 256, 0, stream>>>(loc, conf, prior, dec, hist);
  k_prefix<<<NB, 1024, 0, stream>>>(hist, sbase, cut);
  k_scatter<<<dim3((NP + 255) / 256, NB), 256, 0, stream>>>(conf, sbase, cut, bcnt, keys);
  k_binsort<<<dim3(1024, NB), 64, 0, stream>>>(sbase, bcnt, cut, keys);
  k_emit<<<NB, 1024, 0, stream>>>(keys, dec, tscore, tbox, vmaskp);
  k_mask<<<dim3(NW, NW, NB), 64, 0, stream>>>(tbox, maskp, diagTp);
  k_nms<<<NB, 64, 0, stream>>>(tscore, tbox, vmaskp, maskp, diagTp, out);
}

// Round 12
// 263.681 us; speedup vs baseline: 1.2720x; 1.2720x over previous
//
#include <hip/hip_runtime.h>
#include <math.h>

typedef unsigned long long u64;
typedef unsigned int u32;

#define NP 34125
#define NB 4
#define NTOP 5000
#define TOPK 750
#define NW 79          // ceil(5000/64)
#define TPAD 5120      // padded top-K stride
#define CAP 8192       // slot capacity per image for counting-sort scatter
#define MWORDS 202240  // triangular mask words per image: 64*sum_{c=0..78}(79-c)

// ---- exact-order f32 IoU matching the JAX reference elementwise ops ----
__device__ __forceinline__ float iou_ref(float4 a, float4 b) {
  float areaA = __fmul_rn(__fsub_rn(a.z, a.x), __fsub_rn(a.w, a.y));
  float areaB = __fmul_rn(__fsub_rn(b.z, b.x), __fsub_rn(b.w, b.y));
  float iw = fmaxf(__fsub_rn(fminf(a.z, b.z), fmaxf(a.x, b.x)), 0.0f);
  float ih = fmaxf(__fsub_rn(fminf(a.w, b.w), fmaxf(a.y, b.y)), 0.0f);
  float inter = __fmul_rn(iw, ih);
  float denom = __fsub_rn(__fadd_rn(areaA, areaB), inter);
  return inter / denom;  // 0/0 -> NaN for zero-pad boxes; NaN>0.3f is false (safe)
}

// triangular row offset (in u64 words) of mask row i within one image
__device__ __forceinline__ int row_off_words(int i) {
  int ci = i >> 6;
  int r = i & 63;
  int base = ((ci * 79 - ((ci * (ci - 1)) >> 1)) << 6);
  return base + r * (79 - ci);
}

__device__ __forceinline__ u64 wave_or64(u64 x) {
  for (int d = 1; d < 64; d <<= 1) x |= __shfl_xor(x, d);
  return x;
}

__global__ void k_zero(float* out, u32* hist, u32* bcnt, int* cut, u64* keys) {
  int t = blockIdx.x * 256 + threadIdx.x;
  if (t < 30000) out[t] = 0.0f;
  if (t < 4096) { hist[t] = 0u; bcnt[t] = 0u; }
  if (t < 4) cut[t] = 0;
  if (t < NB * CAP) keys[t] = ~0ull;
}

__global__ void k_decode(const float4* loc, const float* conf, const float4* prior,
                         float4* dec, u32* hist) {
  int p = blockIdx.x * 256 + threadIdx.x;
  int img = blockIdx.y;
  if (p >= NP) return;
  float4 L = loc[(size_t)img * NP + p];
  float4 Pr = prior[p];
  // xy = prior_xy + (loc_xy * 0.1) * prior_wh   (no FMA contraction: explicit _rn ops)
  float ex = __fmul_rn(__fmul_rn(L.x, 0.1f), Pr.z);
  float ey = __fmul_rn(__fmul_rn(L.y, 0.1f), Pr.w);
  float cx = __fadd_rn(Pr.x, ex);
  float cy = __fadd_rn(Pr.y, ey);
  // wh = prior_wh * exp(loc_wh * 0.2) ; exp via double = correctly-rounded f32 exp
  float ww = __fmul_rn(Pr.z, (float)exp((double)__fmul_rn(L.z, 0.2f)));
  float hh = __fmul_rn(Pr.w, (float)exp((double)__fmul_rn(L.w, 0.2f)));
  float x1 = __fsub_rn(cx, __fmul_rn(ww, 0.5f));
  float y1 = __fsub_rn(cy, __fmul_rn(hh, 0.5f));
  float x2 = __fadd_rn(x1, ww);
  float y2 = __fadd_rn(y1, hh);
  dec[(size_t)img * NP + p] = make_float4(x1, y1, x2, y2);
  float s = conf[((size_t)img * NP + p) * 2 + 1];
  if (s > 0.05f) {
    int bin = (int)(s * 1024.0f); if (bin > 1023) bin = 1023;
    atomicAdd(&hist[img * 1024 + bin], 1u);
  }
}

// per image: suffix-scan the 1024-bin histogram -> descending-order base
// position per bin, plus the cutoff bin (suffix count crosses NTOP)
__global__ __launch_bounds__(1024) void k_prefix(const u32* hist, u32* sbase, int* cut) {
  __shared__ u32 buf[1024];
  int img = blockIdx.x, tid = threadIdx.x;
  int b = 1023 - tid;
  u32 c = hist[img * 1024 + b];
  buf[tid] = c;
  __syncthreads();
  for (int off = 1; off < 1024; off <<= 1) {
    u32 v = (tid >= off) ? buf[tid - off] : 0u;
    __syncthreads();
    buf[tid] += v;
    __syncthreads();
  }
  u32 S = buf[tid];                 // inclusive suffix count for bin b
  sbase[img * 1024 + b] = S - c;    // # elements in strictly-higher bins
  if (S >= NTOP && (S - c) < NTOP) cut[img] = b;  // unique crossing thread
}

// scatter each above-cutoff candidate to its exact descending position
// (bin base + arrival rank); within-bin order fixed later by k_binsort
__global__ void k_scatter(const float* conf, const u32* sbase, const int* cut,
                          u32* bcnt, u64* keys) {
  int p = blockIdx.x * 256 + threadIdx.x;
  int img = blockIdx.y;
  if (p >= NP) return;
  float s = conf[((size_t)img * NP + p) * 2 + 1];
  if (!(s > 0.05f)) return;
  int bin = (int)(s * 1024.0f); if (bin > 1023) bin = 1023;
  if (bin < cut[img]) return;
  u32 r = atomicAdd(&bcnt[img * 1024 + bin], 1u);
  u32 slot = sbase[img * 1024 + bin] + r;
  if (slot < CAP)
    keys[(size_t)img * CAP + slot] = (((u64)(~__float_as_uint(s))) << 32) | (u32)p;
}

// full ascending sort of 64 u64 keys across one wave (21 shfl_xor steps)
__device__ __forceinline__ u64 sort64(u64 x, int lane) {
  for (int k = 2; k <= 64; k <<= 1) {
    for (int j = k >> 1; j > 0; j >>= 1) {
      u64 v = __shfl_xor(x, j);
      bool keepMin = (((lane & j) == 0) == ((lane & k) == 0));
      u64 mn = x < v ? x : v;
      u64 mx = x < v ? v : x;
      x = keepMin ? mn : mx;
    }
  }
  return x;
}

// one wave per bin: sort that bin's slot range in place
// key = (~score_bits, idx) ascending  => score desc, idx asc (lax.top_k ties)
__global__ __launch_bounds__(64) void k_binsort(const u32* sbase, const u32* bcnt,
                                                const int* cut, u64* keys) {
  int b = blockIdx.x, img = blockIdx.y;
  if (b < cut[img]) return;
  u32 n = bcnt[img * 1024 + b];
  if (n == 0) return;
  u32 base = sbase[img * 1024 + b];
  if (base >= CAP) return;
  if (n > CAP - base) n = CAP - base;
  u64* seg = keys + (size_t)img * CAP + base;
  int lane = threadIdx.x;
  if (n <= 64) {
    u64 key = (lane < (int)n) ? seg[lane] : ~0ull;
    key = sort64(key, lane);
    if (lane < (int)n) seg[lane] = key;
  } else {
    // rare fallback: in-LDS bitonic, single wave, up to 1024 elements
    __shared__ u64 sbuf[1024];
    if (n > 1024) n = 1024;
    int npow2 = 128;
    while (npow2 < (int)n) npow2 <<= 1;
    for (int t = lane; t < npow2; t += 64) sbuf[t] = (t < (int)n) ? seg[t] : ~0ull;
    __syncthreads();
    for (int k = 2; k <= npow2; k <<= 1) {
      for (int j = k >> 1; j > 0; j >>= 1) {
        for (int t = lane; t < npow2; t += 64) {
          int ixj = t ^ j;
          if (ixj > t) {
            u64 a = sbuf[t], bb = sbuf[ixj];
            bool up = ((t & k) == 0);
            if ((a > bb) == up) { sbuf[t] = bb; sbuf[ixj] = a; }
          }
        }
        __syncthreads();
      }
    }
    for (int t = lane; t < (int)n; t += 64) seg[t] = sbuf[t];
  }
}

// emit sorted top-5000: scores, gathered boxes, validity bitmask
__global__ __launch_bounds__(1024) void k_emit(const u64* keys, const float4* dec,
                                               float* tscore, float4* tbox, u64* vmask) {
  int img = blockIdx.x;
  int tid = threadIdx.x;
  int lane = tid & 63;
  const u64* kimg = keys + (size_t)img * CAP;
  for (int i = tid; i < NTOP; i += 1024) {
    u64 key = kimg[i];
    u32 sb = ~(u32)(key >> 32);
    float s = __uint_as_float(sb);
    u32 pidx = (u32)(key & 0xffffffffu);
    tscore[img * TPAD + i] = s;
    float4 bx;
    if (key != ~0ull) bx = dec[(size_t)img * NP + pidx];
    else bx = make_float4(0.f, 0.f, 0.f, 0.f);
    tbox[img * TPAD + i] = bx;
    bool valid = (key != ~0ull) && (s > 0.05f);
    u64 bal = __ballot(valid);
    if (lane == 0) vmask[img * 80 + (i >> 6)] = bal;
  }
}

// parallel suppression-bitmask: 64x64 tiles, upper triangle, triangular storage.
// Diagonal blocks additionally emit the TRANSPOSED tile (lane l holds column l:
// bit k = "k suppresses l"), built with 64 ballots.
__global__ __launch_bounds__(64) void k_mask(const float4* tbox, u64* mask, u64* diagT) {
  int ci = blockIdx.x, cj = blockIdx.y, img = blockIdx.z;
  if (cj < ci) return;
  int lane = threadIdx.x;
  __shared__ float4 jb[64];
  int j0 = cj * 64;
  int jj = j0 + lane;
  jb[lane] = (jj < NTOP) ? tbox[img * TPAD + jj] : make_float4(0.f, 0.f, 0.f, 0.f);
  __syncthreads();
  int i = ci * 64 + lane;
  if (i >= NTOP) return;
  float4 bi = tbox[img * TPAD + i];
  u64 word = 0;
  for (int q = 0; q < 64; ++q) {
    int j = j0 + q;
    if (j > i && j < NTOP) {
      if (iou_ref(bi, jb[q]) > 0.3f) word |= (1ull << q);
    }
  }
  u64* mrow = mask + (size_t)img * MWORDS + row_off_words(i);
  mrow[cj - ci] = word;
  if (ci == cj) {
    u64 colw = 0ull;
    for (int t = 0; t < 64; ++t) {
      u64 b = __ballot((word >> t) & 1ull);  // bit l of b = row l's bit t => column t
      if (lane == t) colw = b;
    }
    diagT[((size_t)img * 80 + ci) * 64 + lane] = colw;
  }
}

// greedy NMS, 4-wave producer/consumer: one 256-thread block per image.
// Wave 0 (greedy owner): per word f, uniform LDS read rem[f] | register carry
// -> ballot-greedy on diagT (coalesced reg prefetch, its ONLY global loads)
// -> publish kept -> carry for f+1 via LDS superdiag column. No scattered
// loads, no staging arrays in wave 0's instruction stream.
// Waves 1-3 (workers): at step f, OR keeps(f-1)'s rows into LDS rem[f+1..78]
// (8-deep batched coalesced loads, one wait, atomicOr to LDS). Wave 3 also
// stages the superdiag column of word f+2 into an LDS ring. Worker waitcnt
// stalls overlap wave 0's greedy (TLP, not ILP).
// One __syncthreads per word: keeps(g<=f-2) reach rem[f] via workers by end
// of step f-1; keeps(f-1) reach word f via the carry. Induction complete.
__global__ __launch_bounds__(256, 1) void k_nms(const float* tscore, const float4* tbox,
                                                const u64* vmask, const u64* mask,
                                                const u64* diagT, float* out) {
  int img = blockIdx.x;
  int tid = threadIdx.x;
  int wid = tid >> 6;
  int lane = tid & 63;
  const u64* mimg = mask + (size_t)img * MWORDS;
  const u64* dT = diagT + (size_t)img * 80 * 64;

  __shared__ u64 rem[80];
  __shared__ u64 vld[80];
  __shared__ u64 sdiag[4][64];   // superdiag ring: sdiag[f&3][l] = mask[(f<<6)+l][word f+1]
  __shared__ int klist[2][64];   // kept indices, parity ring
  __shared__ int kcnt[2];
  __shared__ int list[TOPK];
  __shared__ int lds_nk;
  __shared__ int lds_done;

  for (int w = tid; w < 80; w += 256) {
    rem[w] = 0ull;
    vld[w] = (w < NW) ? vmask[img * 80 + w] : 0ull;
  }
  if (tid == 0) { lds_nk = 0; lds_done = 0; kcnt[0] = 0; kcnt[1] = 0; }
  if (wid == 1) {  // prologue: superdiag for words 0,1
    int i0 = lane;
    sdiag[0][lane] = (i0 < NTOP && 1 < NW) ? mimg[row_off_words(i0) + 1] : 0ull;
  }
  if (wid == 2) {
    int i1 = 64 + lane;
    sdiag[1][lane] = (i1 < NTOP && 2 < NW) ? mimg[row_off_words(i1) + 1] : 0ull;
  }
  __syncthreads();

  // wave-0 persistent state
  u64 carry = 0ull;
  u64 c0 = 0, c1 = 0;
  int nk = 0;
  if (wid == 0) { c0 = dT[lane]; c1 = dT[64 + lane]; }

  for (int f = 0; f < NW; ++f) {
    if (wid == 0) {
      // ---- greedy owner ----
      u64 colT = (f & 1) ? c1 : c0;
      if (f + 2 < NW) { u64 nc = dT[(f + 2) * 64 + lane]; if (f & 1) c1 = nc; else c0 = nc; }
      u64 remf = rem[f] | carry;   // uniform LDS broadcast
      u64 vldf = vld[f];
      carry = 0ull;
      u64 live = vldf & ~remf;
      u64 kept = 0ull;
      while (live) {
        int k = __builtin_ctzll(live);
        kept |= (1ull << k);
        u64 sup = __ballot((colT >> k) & 1ull);  // bit l = "k suppresses l" (l>k)
        live &= ~((1ull << k) | sup);
      }
      int cap = TOPK - nk;
      int nkw = __builtin_popcountll(kept);
      if (nkw > cap) {  // truncate to lowest `cap` set bits (greedy order)
        for (int d = nkw - cap; d > 0; --d) kept &= ~(1ull << (63 - __builtin_clzll(kept)));
        nkw = cap;
      }
      int rank = __builtin_popcountll(kept & ((1ull << lane) - 1ull));
      bool mine = (kept >> lane) & 1ull;
      if (mine) { list[nk + rank] = (f << 6) + lane; klist[f & 1][rank] = (f << 6) + lane; }
      if (lane == 0) kcnt[f & 1] = nkw;
      nk += nkw;
      if (lane == 0) lds_nk = nk;
      if (nk >= TOPK) {
        if (lane == 0) lds_done = 1;
      } else if (f + 1 < NW) {
        // carry: keeps(f) -> rem[f+1], register-only via LDS superdiag
        u64 sd = sdiag[f & 3][lane];
        carry = wave_or64(mine ? sd : 0ull);
      }
    } else {
      // ---- workers: push keeps(f-1) into rem[f+1..NW-1] ----
      int span = NW - 1 - f;  // target words f+1..NW-1
      if (wid == 3 && f + 3 < NW) {
        // stage superdiag column of word f+2 (used by wave 0 at step f+2)
        int i = ((f + 2) << 6) + lane;
        sdiag[(f + 2) & 3][lane] = (i < NTOP) ? mimg[row_off_words(i) + 1] : 0ull;
      }
      if (f >= 1 && span > 0) {
        int pf = (f - 1) & 1;
        int nkp = kcnt[pf];
        for (int t0 = wid - 1; t0 < nkp; t0 += 24) {
          u64 g[8], h[8];
#pragma unroll
          for (int u = 0; u < 8; ++u) {
            int r = t0 + u * 3;
            bool ok = r < nkp;
            int i = klist[pf][ok ? r : 0];
            const u64* row = mimg + row_off_words(i);  // row word 0 == word f-1
            g[u] = (ok && lane < span) ? row[lane + 2] : 0ull;
            h[u] = (ok && lane + 64 < span) ? row[lane + 66] : 0ull;
          }
          u64 acc = g[0] | g[1] | g[2] | g[3] | g[4] | g[5] | g[6] | g[7];
          u64 acc2 = h[0] | h[1] | h[2] | h[3] | h[4] | h[5] | h[6] | h[7];
          if (lane < span && acc) atomicOr(&rem[f + 1 + lane], acc);
          if (lane + 64 < span && acc2) atomicOr(&rem[f + 65 + lane], acc2);
        }
      }
    }
    __syncthreads();
    if (lds_done) break;
  }

  __syncthreads();
  int fnk = lds_nk;
  float* o = out + (size_t)(img * 2 + 1) * TOPK * 5;
  for (int r = tid; r < fnk; r += 256) {
    int i = list[r];
    float s = tscore[img * TPAD + i];
    float4 b = tbox[img * TPAD + i];
    o[r * 5 + 0] = s;
    o[r * 5 + 1] = b.x;
    o[r * 5 + 2] = b.y;
    o[r * 5 + 3] = b.z;
    o[r * 5 + 4] = b.w;
  }
}

extern "C" void kernel_launch(void* const* d_in, const int* in_sizes, int n_in,
                              void* d_out, int out_size, void* d_ws, size_t ws_size,
                              hipStream_t stream) {
  const float4* loc   = (const float4*)d_in[0];
  const float*  conf  = (const float*)d_in[1];
  const float4* prior = (const float4*)d_in[2];
  float* out = (float*)d_out;
  char* ws = (char*)d_ws;

  // ws layout (256B-aligned offsets), total ~9.55MB
  float4* dec    = (float4*)(ws + 0);          // 4*34125*16 = 2,184,000
  u32*    hist   = (u32*)  (ws + 2184192);     // 4*1024*4   = 16,384
  u32*    bcnt   = (u32*)  (ws + 2200576);     // 4*1024*4   = 16,384
  u32*    sbase  = (u32*)  (ws + 2216960);     // 4*1024*4   = 16,384
  int*    cut    = (int*)  (ws + 2233344);     // 16 (pad to 256)
  u64*    keys   = (u64*)  (ws + 2233600);     // 4*8192*8   = 262,144
  float*  tscore = (float*)(ws + 2495744);     // 4*5120*4   = 81,920
  float4* tbox   = (float4*)(ws + 2577664);    // 4*5120*16  = 327,680
  u64*    vmaskp = (u64*)  (ws + 2905344);     // 4*80*8     = 2,560 (pad to 2,908,160)
  u64*    maskp  = (u64*)  (ws + 2908160);     // 4*202240*8 = 6,471,680 -> 9,379,840
  u64*    diagTp = (u64*)  (ws + 9379840);     // 4*80*64*8  = 163,840   -> 9,543,680

  k_zero<<<dim3(128), 256, 0, stream>>>(out, hist, bcnt, cut, keys);
  k_decode<<<dim3((NP + 255) / 256, NB), 256, 0, stream>>>(loc, conf, prior, dec, hist);
  k_prefix<<<NB, 1024, 0, stream>>>(hist, sbase, cut);
  k_scatter<<<dim3((NP + 255) / 256, NB), 256, 0, stream>>>(conf, sbase, cut, bcnt, keys);
  k_binsort<<<dim3(1024, NB), 64, 0, stream>>>(sbase, bcnt, cut, keys);
  k_emit<<<NB, 1024, 0, stream>>>(keys, dec, tscore, tbox, vmaskp);
  k_mask<<<dim3(NW, NW, NB), 64, 0, stream>>>(tbox, maskp, diagTp);
  k_nms<<<NB, 256, 0, stream>>>(tscore, tbox, vmaskp, maskp, diagTp, out);
}

// Round 14
// 238.899 us; speedup vs baseline: 1.4040x; 1.1037x over previous
//
#include <hip/hip_runtime.h>
#include <math.h>

typedef unsigned long long u64;
typedef unsigned int u32;

#define NP 34125
#define NB 4
#define NTOP 5000
#define TOPK 750
#define NW 79          // ceil(5000/64)
#define TPAD 5120      // padded top-K stride
#define CAP 8192       // slot capacity per image for counting-sort scatter
#define MWORDS 202240  // triangular mask words per image: 64*sum_{c=0..78}(79-c)

// ---- exact-order f32 IoU matching the JAX reference elementwise ops ----
__device__ __forceinline__ float iou_ref(float4 a, float4 b) {
  float areaA = __fmul_rn(__fsub_rn(a.z, a.x), __fsub_rn(a.w, a.y));
  float areaB = __fmul_rn(__fsub_rn(b.z, b.x), __fsub_rn(b.w, b.y));
  float iw = fmaxf(__fsub_rn(fminf(a.z, b.z), fmaxf(a.x, b.x)), 0.0f);
  float ih = fmaxf(__fsub_rn(fminf(a.w, b.w), fmaxf(a.y, b.y)), 0.0f);
  float inter = __fmul_rn(iw, ih);
  float denom = __fsub_rn(__fadd_rn(areaA, areaB), inter);
  return inter / denom;  // 0/0 -> NaN for zero-pad boxes; NaN>0.3f is false (safe)
}

// triangular row offset (in u64 words) of mask row i within one image
__device__ __forceinline__ int row_off_words(int i) {
  int ci = i >> 6;
  int r = i & 63;
  int base = ((ci * 79 - ((ci * (ci - 1)) >> 1)) << 6);
  return base + r * (79 - ci);
}

__global__ void k_zero(float* out, u32* hist, u32* bcnt, int* cut, u64* keys) {
  int t = blockIdx.x * 256 + threadIdx.x;
  if (t < 30000) out[t] = 0.0f;
  if (t < 4096) { hist[t] = 0u; bcnt[t] = 0u; }
  if (t < 4) cut[t] = 0;
  if (t < NB * CAP) keys[t] = ~0ull;
}

__global__ void k_decode(const float4* loc, const float* conf, const float4* prior,
                         float4* dec, u32* hist) {
  int p = blockIdx.x * 256 + threadIdx.x;
  int img = blockIdx.y;
  if (p >= NP) return;
  float4 L = loc[(size_t)img * NP + p];
  float4 Pr = prior[p];
  // xy = prior_xy + (loc_xy * 0.1) * prior_wh   (no FMA contraction: explicit _rn ops)
  float ex = __fmul_rn(__fmul_rn(L.x, 0.1f), Pr.z);
  float ey = __fmul_rn(__fmul_rn(L.y, 0.1f), Pr.w);
  float cx = __fadd_rn(Pr.x, ex);
  float cy = __fadd_rn(Pr.y, ey);
  // wh = prior_wh * exp(loc_wh * 0.2) ; exp via double = correctly-rounded f32 exp
  float ww = __fmul_rn(Pr.z, (float)exp((double)__fmul_rn(L.z, 0.2f)));
  float hh = __fmul_rn(Pr.w, (float)exp((double)__fmul_rn(L.w, 0.2f)));
  float x1 = __fsub_rn(cx, __fmul_rn(ww, 0.5f));
  float y1 = __fsub_rn(cy, __fmul_rn(hh, 0.5f));
  float x2 = __fadd_rn(x1, ww);
  float y2 = __fadd_rn(y1, hh);
  dec[(size_t)img * NP + p] = make_float4(x1, y1, x2, y2);
  float s = conf[((size_t)img * NP + p) * 2 + 1];
  if (s > 0.05f) {
    int bin = (int)(s * 1024.0f); if (bin > 1023) bin = 1023;
    atomicAdd(&hist[img * 1024 + bin], 1u);
  }
}

// per image: suffix-scan the 1024-bin histogram -> descending-order base
// position per bin, plus the cutoff bin (suffix count crosses NTOP)
__global__ __launch_bounds__(1024) void k_prefix(const u32* hist, u32* sbase, int* cut) {
  __shared__ u32 buf[1024];
  int img = blockIdx.x, tid = threadIdx.x;
  int b = 1023 - tid;
  u32 c = hist[img * 1024 + b];
  buf[tid] = c;
  __syncthreads();
  for (int off = 1; off < 1024; off <<= 1) {
    u32 v = (tid >= off) ? buf[tid - off] : 0u;
    __syncthreads();
    buf[tid] += v;
    __syncthreads();
  }
  u32 S = buf[tid];                 // inclusive suffix count for bin b
  sbase[img * 1024 + b] = S - c;    // # elements in strictly-higher bins
  if (S >= NTOP && (S - c) < NTOP) cut[img] = b;  // unique crossing thread
}

// scatter each above-cutoff candidate to its exact descending position
// (bin base + arrival rank); within-bin order fixed later by k_binsort
__global__ void k_scatter(const float* conf, const u32* sbase, const int* cut,
                          u32* bcnt, u64* keys) {
  int p = blockIdx.x * 256 + threadIdx.x;
  int img = blockIdx.y;
  if (p >= NP) return;
  float s = conf[((size_t)img * NP + p) * 2 + 1];
  if (!(s > 0.05f)) return;
  int bin = (int)(s * 1024.0f); if (bin > 1023) bin = 1023;
  if (bin < cut[img]) return;
  u32 r = atomicAdd(&bcnt[img * 1024 + bin], 1u);
  u32 slot = sbase[img * 1024 + bin] + r;
  if (slot < CAP)
    keys[(size_t)img * CAP + slot] = (((u64)(~__float_as_uint(s))) << 32) | (u32)p;
}

// full ascending sort of 64 u64 keys across one wave (21 shfl_xor steps)
__device__ __forceinline__ u64 sort64(u64 x, int lane) {
  for (int k = 2; k <= 64; k <<= 1) {
    for (int j = k >> 1; j > 0; j >>= 1) {
      u64 v = __shfl_xor(x, j);
      bool keepMin = (((lane & j) == 0) == ((lane & k) == 0));
      u64 mn = x < v ? x : v;
      u64 mx = x < v ? v : x;
      x = keepMin ? mn : mx;
    }
  }
  return x;
}

// one wave per bin: sort that bin's slot range in place
// key = (~score_bits, idx) ascending  => score desc, idx asc (lax.top_k ties)
__global__ __launch_bounds__(64) void k_binsort(const u32* sbase, const u32* bcnt,
                                                const int* cut, u64* keys) {
  int b = blockIdx.x, img = blockIdx.y;
  if (b < cut[img]) return;
  u32 n = bcnt[img * 1024 + b];
  if (n == 0) return;
  u32 base = sbase[img * 1024 + b];
  if (base >= CAP) return;
  if (n > CAP - base) n = CAP - base;
  u64* seg = keys + (size_t)img * CAP + base;
  int lane = threadIdx.x;
  if (n <= 64) {
    u64 key = (lane < (int)n) ? seg[lane] : ~0ull;
    key = sort64(key, lane);
    if (lane < (int)n) seg[lane] = key;
  } else {
    // rare fallback: in-LDS bitonic, single wave, up to 1024 elements
    __shared__ u64 sbuf[1024];
    if (n > 1024) n = 1024;
    int npow2 = 128;
    while (npow2 < (int)n) npow2 <<= 1;
    for (int t = lane; t < npow2; t += 64) sbuf[t] = (t < (int)n) ? seg[t] : ~0ull;
    __syncthreads();
    for (int k = 2; k <= npow2; k <<= 1) {
      for (int j = k >> 1; j > 0; j >>= 1) {
        for (int t = lane; t < npow2; t += 64) {
          int ixj = t ^ j;
          if (ixj > t) {
            u64 a = sbuf[t], bb = sbuf[ixj];
            bool up = ((t & k) == 0);
            if ((a > bb) == up) { sbuf[t] = bb; sbuf[ixj] = a; }
          }
        }
        __syncthreads();
      }
    }
    for (int t = lane; t < (int)n; t += 64) seg[t] = sbuf[t];
  }
}

// emit sorted top-5000: scores, gathered boxes, validity bitmask
__global__ __launch_bounds__(1024) void k_emit(const u64* keys, const float4* dec,
                                               float* tscore, float4* tbox, u64* vmask) {
  int img = blockIdx.x;
  int tid = threadIdx.x;
  int lane = tid & 63;
  const u64* kimg = keys + (size_t)img * CAP;
  for (int i = tid; i < NTOP; i += 1024) {
    u64 key = kimg[i];
    u32 sb = ~(u32)(key >> 32);
    float s = __uint_as_float(sb);
    u32 pidx = (u32)(key & 0xffffffffu);
    tscore[img * TPAD + i] = s;
    float4 bx;
    if (key != ~0ull) bx = dec[(size_t)img * NP + pidx];
    else bx = make_float4(0.f, 0.f, 0.f, 0.f);
    tbox[img * TPAD + i] = bx;
    bool valid = (key != ~0ull) && (s > 0.05f);
    u64 bal = __ballot(valid);
    if (lane == 0) vmask[img * 80 + (i >> 6)] = bal;
  }
}

// parallel suppression-bitmask: 64x64 tiles, upper triangle, triangular storage.
// Diagonal blocks additionally emit the TRANSPOSED tile (lane l holds column l:
// bit k = "k suppresses l"), built with 64 ballots.
__global__ __launch_bounds__(64) void k_mask(const float4* tbox, u64* mask, u64* diagT) {
  int ci = blockIdx.x, cj = blockIdx.y, img = blockIdx.z;
  if (cj < ci) return;
  int lane = threadIdx.x;
  __shared__ float4 jb[64];
  int j0 = cj * 64;
  int jj = j0 + lane;
  jb[lane] = (jj < NTOP) ? tbox[img * TPAD + jj] : make_float4(0.f, 0.f, 0.f, 0.f);
  __syncthreads();
  int i = ci * 64 + lane;
  if (i >= NTOP) return;
  float4 bi = tbox[img * TPAD + i];
  u64 word = 0;
  for (int q = 0; q < 64; ++q) {
    int j = j0 + q;
    if (j > i && j < NTOP) {
      if (iou_ref(bi, jb[q]) > 0.3f) word |= (1ull << q);
    }
  }
  u64* mrow = mask + (size_t)img * MWORDS + row_off_words(i);
  mrow[cj - ci] = word;
  if (ci == cj) {
    u64 colw = 0ull;
    for (int t = 0; t < 64; ++t) {
      u64 b = __ballot((word >> t) & 1ull);  // bit l of b = row l's bit t => column t
      if (lane == t) colw = b;
    }
    diagT[((size_t)img * 80 + ci) * 64 + lane] = colw;
  }
}

// greedy NMS, 8-wave producer/consumer with 2-step-slack pipelined pushes.
// Wave 0 (greedy): per word f touches ONLY LDS/registers: rem[f] | cA | cBu
// -> ballot-greedy on LDS-staged diagT -> dual fused wave-OR of sd1/sd2
// (keeps(f)->rem[f+1] and ->rem[f+2] carries). Zero global loads in wave 0.
// Waves 1-6 (pushers, pipelined): issue keeps(f-1) row loads into registers
// at step f, commit via LDS atomicOr into rem[(f-1)+3..] at step f+1 -> the
// vmcnt wait sits a full step after issue (2-step deadline met with slack).
// Wave 7 (tiles): stages diagT column + sd1/sd2 (row words +1,+2) for word
// f+2 into LDS rings (issue at f, commit at f+1); also rare >48-keep overflow.
__global__ __launch_bounds__(512, 1) void k_nms(const float* tscore, const float4* tbox,
                                                const u64* vmask, const u64* mask,
                                                const u64* diagT, float* out) {
  int img = blockIdx.x;
  int tid = threadIdx.x;
  int wid = tid >> 6;
  int lane = tid & 63;
  const u64* mimg = mask + (size_t)img * MWORDS;
  const u64* dT = diagT + (size_t)img * 80 * 64;

  __shared__ u64 rem[80];
  __shared__ u64 vld[80];
  __shared__ u64 cTr[4][64];   // diagT column ring
  __shared__ u64 sd1r[4][64];  // row word +1 ring (superdiag)
  __shared__ u64 sd2r[4][64];  // row word +2 ring
  __shared__ int klist[4][64];
  __shared__ int kcnt[4];
  __shared__ int list[TOPK];
  __shared__ int lds_nk;
  __shared__ int lds_done;

  for (int w = tid; w < 80; w += 512) {
    rem[w] = 0ull;
    vld[w] = (w < NW) ? vmask[img * 80 + w] : 0ull;
  }
  if (tid == 0) { lds_nk = 0; lds_done = 0; }
  if (tid < 4) kcnt[tid] = 0;
  // prologue: stage ring slots 0 and 1 synchronously
  if (wid == 1) {
    cTr[0][lane] = dT[lane];
    const u64* row = mimg + row_off_words(lane);
    sd1r[0][lane] = row[1];
    sd2r[0][lane] = row[2];
  } else if (wid == 2) {
    cTr[1][lane] = dT[64 + lane];
    const u64* row = mimg + row_off_words(64 + lane);
    sd1r[1][lane] = row[1];
    sd2r[1][lane] = row[2];
  }
  __syncthreads();

  // persistent per-wave state
  u64 cA = 0ull, cBu = 0ull, cBn = 0ull;  // wave 0 carries
  int nk = 0;
  u64 wg[8], wh[8];                       // worker staged rows
  int wpend = -1;
  u64 tc = 0, t1 = 0, t2 = 0;             // tile stage
  int tpend = -1;

  for (int f = 0; f < NW; ++f) {
    if (wid == 0) {
      // ---- greedy owner: LDS/register only ----
      u64 colT = cTr[f & 3][lane];
      u64 remf = rem[f] | cA | cBu;
      u64 live = vld[f] & ~remf;
      u64 kept = 0ull;
      while (live) {
        int k = __builtin_ctzll(live);
        kept |= (1ull << k);
        u64 sup = __ballot((colT >> k) & 1ull);  // bit l = "k suppresses l" (l>k)
        live &= ~((1ull << k) | sup);
      }
      int cap = TOPK - nk;
      int nkw = __builtin_popcountll(kept);
      if (nkw > cap) {  // truncate to lowest `cap` bits (greedy order)
        for (int d = nkw - cap; d > 0; --d) kept &= ~(1ull << (63 - __builtin_clzll(kept)));
        nkw = cap;
      }
      int rank = __builtin_popcountll(kept & ((1ull << lane) - 1ull));
      bool mine = (kept >> lane) & 1ull;
      if (mine) { list[nk + rank] = (f << 6) + lane; klist[f & 3][rank] = (f << 6) + lane; }
      if (lane == 0) kcnt[f & 3] = nkw;
      nk += nkw;
      if (lane == 0) lds_nk = nk;
      if (nk >= TOPK) {
        if (lane == 0) lds_done = 1;
      } else {
        // dual carry: keeps(f)->rem[f+1] (sd1) and ->rem[f+2] (sd2), fused butterfly
        u64 a = mine ? sd1r[f & 3][lane] : 0ull;
        u64 b = mine ? sd2r[f & 3][lane] : 0ull;
        for (int d = 1; d < 64; d <<= 1) { a |= __shfl_xor(a, d); b |= __shfl_xor(b, d); }
        cA = a; cBu = cBn; cBn = b;
      }
    } else if (wid <= 6) {
      // ---- pushers: commit last step's staged rows, then issue keeps(f-1) ----
      if (wpend >= 0) {
        int base = wpend + 3;
        u64 acc = wg[0] | wg[1] | wg[2] | wg[3] | wg[4] | wg[5] | wg[6] | wg[7];
        u64 acc2 = wh[0] | wh[1] | wh[2] | wh[3] | wh[4] | wh[5] | wh[6] | wh[7];
        if (base + lane < NW && acc) atomicOr(&rem[base + lane], acc);
        if (base + 64 + lane < NW && acc2) atomicOr(&rem[base + 64 + lane], acc2);
        wpend = -1;
      }
      int gword = f - 1;
      if (gword >= 0) {
        int nkp = kcnt[gword & 3];
        int span = NW - (gword + 3);      // lane targets (gword+3)+lane
        int r0 = (wid - 1) * 8;
        if (span > 0 && r0 < nkp) {
#pragma unroll
          for (int u = 0; u < 8; ++u) {
            int r = r0 + u;
            bool ok = r < nkp;
            int i = klist[gword & 3][ok ? r : 0];
            const u64* row = mimg + row_off_words(i);  // row word 0 == word gword
            wg[u] = (ok && lane < span) ? row[3 + lane] : 0ull;
            wh[u] = (ok && lane + 64 < span) ? row[67 + lane] : 0ull;
          }
          wpend = gword;
        }
      }
    } else {
      // ---- wave 7: tile staging (issue f+2, commit previous) + overflow ----
      if (tpend >= 0) {
        int s = tpend & 3;
        cTr[s][lane] = tc; sd1r[s][lane] = t1; sd2r[s][lane] = t2;
        tpend = -1;
      }
      int slot = f + 2;
      if (slot < NW) {
        tc = dT[slot * 64 + lane];
        int i = (slot << 6) + lane;
        if (i < NTOP) {
          const u64* row = mimg + row_off_words(i);
          t1 = (slot + 1 < NW) ? row[1] : 0ull;
          t2 = (slot + 2 < NW) ? row[2] : 0ull;
        } else { t1 = 0ull; t2 = 0ull; }
        tpend = slot;
      }
      int gword = f - 1;  // overflow rows beyond 48 (extremely rare): immediate
      if (gword >= 0) {
        int nkp = kcnt[gword & 3];
        int base = gword + 3;
        for (int r = 48; r < nkp; ++r) {
          int i = klist[gword & 3][r];
          const u64* row = mimg + row_off_words(i);
          if (base + lane < NW) { u64 v = row[3 + lane]; if (v) atomicOr(&rem[base + lane], v); }
          if (base + 64 + lane < NW) { u64 v = row[67 + lane]; if (v) atomicOr(&rem[base + 64 + lane], v); }
        }
      }
    }
    __syncthreads();
    if (lds_done) break;
  }

  __syncthreads();
  int fnk = lds_nk;
  float* o = out + (size_t)(img * 2 + 1) * TOPK * 5;
  for (int r = tid; r < fnk; r += 512) {
    int i = list[r];
    float s = tscore[img * TPAD + i];
    float4 b = tbox[img * TPAD + i];
    o[r * 5 + 0] = s;
    o[r * 5 + 1] = b.x;
    o[r * 5 + 2] = b.y;
    o[r * 5 + 3] = b.z;
    o[r * 5 + 4] = b.w;
  }
}

extern "C" void kernel_launch(void* const* d_in, const int* in_sizes, int n_in,
                              void* d_out, int out_size, void* d_ws, size_t ws_size,
                              hipStream_t stream) {
  const float4* loc   = (const float4*)d_in[0];
  const float*  conf  = (const float*)d_in[1];
  const float4* prior = (const float4*)d_in[2];
  float* out = (float*)d_out;
  char* ws = (char*)d_ws;

  // ws layout (256B-aligned offsets), total ~9.55MB
  float4* dec    = (float4*)(ws + 0);          // 4*34125*16 = 2,184,000
  u32*    hist   = (u32*)  (ws + 2184192);     // 4*1024*4   = 16,384
  u32*    bcnt   = (u32*)  (ws + 2200576);     // 4*1024*4   = 16,384
  u32*    sbase  = (u32*)  (ws + 2216960);     // 4*1024*4   = 16,384
  int*    cut    = (int*)  (ws + 2233344);     // 16 (pad to 256)
  u64*    keys   = (u64*)  (ws + 2233600);     // 4*8192*8   = 262,144
  float*  tscore = (float*)(ws + 2495744);     // 4*5120*4   = 81,920
  float4* tbox   = (float4*)(ws + 2577664);    // 4*5120*16  = 327,680
  u64*    vmaskp = (u64*)  (ws + 2905344);     // 4*80*8     = 2,560 (pad to 2,908,160)
  u64*    maskp  = (u64*)  (ws + 2908160);     // 4*202240*8 = 6,471,680 -> 9,379,840
  u64*    diagTp = (u64*)  (ws + 9379840);     // 4*80*64*8  = 163,840   -> 9,543,680

  k_zero<<<dim3(128), 256, 0, stream>>>(out, hist, bcnt, cut, keys);
  k_decode<<<dim3((NP + 255) / 256, NB), 256, 0, stream>>>(loc, conf, prior, dec, hist);
  k_prefix<<<NB, 1024, 0, stream>>>(hist, sbase, cut);
  k_scatter<<<dim3((NP + 255) / 256, NB), 256, 0, stream>>>(conf, sbase, cut, bcnt, keys);
  k_binsort<<<dim3(1024, NB), 64, 0, stream>>>(sbase, bcnt, cut, keys);
  k_emit<<<NB, 1024, 0, stream>>>(keys, dec, tscore, tbox, vmaskp);
  k_mask<<<dim3(NW, NW, NB), 64, 0, stream>>>(tbox, maskp, diagTp);
  k_nms<<<NB, 512, 0, stream>>>(tscore, tbox, vmaskp, maskp, diagTp, out);
}